// Round 5
// baseline (304.584 us; speedup 1.0000x reference)
//
#include <hip/hip_runtime.h>

#define BB 64
#define TT 32
#define VV 50257
#define NSEG 8
#define SEGLEN 6284          // multiple of 4; 8*6284 = 50272 >= VV
#define GRID1 2048

// Fused kernel: streaming sum-exp over valid segments (barrier-free hot loop,
// per-wave partial stores), then last-finishing block computes the whole loss.
__global__ __launch_bounds__(256) void fused_loss(
    const float* __restrict__ logits,   // [B,T,V]
    const int*   __restrict__ labels,   // [B,T]
    const int*   __restrict__ lens,     // [B]
    unsigned*    __restrict__ counter,  // zeroed each launch
    float*       __restrict__ partial,  // [B*T][NSEG][4] per-wave sums
    float*       __restrict__ numer,    // [B*T][T]
    float*       __restrict__ out)      // [1]
{
    __shared__ int cum[BB + 1];
    __shared__ int sh_last;
    const int tid = threadIdx.x;
    const int wv  = tid >> 6;

    if (tid < 64) {
        int inc = lens[tid];
        #pragma unroll
        for (int off = 1; off < 64; off <<= 1) {
            int o = __shfl_up(inc, off);
            if (tid >= off) inc += o;
        }
        cum[tid + 1] = inc;
        if (tid == 0) cum[0] = 0;
    }
    __syncthreads();
    const int total_sids = cum[BB] * NSEG;

    const int sid_lo = (int)(((long long)blockIdx.x * total_sids) / GRID1);
    const int sid_hi = (int)(((long long)(blockIdx.x + 1) * total_sids) / GRID1);

    for (int sid = sid_lo; sid < sid_hi; ++sid) {
        const int r   = sid >> 3;
        const int seg = sid & (NSEG - 1);

        int lo = 0, hi = BB;                 // largest b with cum[b] <= r
        #pragma unroll
        for (int it = 0; it < 6; ++it) {
            const int mid = (lo + hi) >> 1;
            if (cum[mid] <= r) lo = mid; else hi = mid;
        }
        const int b  = lo;
        const int t  = r - cum[b];
        const int bt = b * TT + t;

        const float* row = logits + (size_t)bt * VV;
        const int seg_lo = seg * SEGLEN;
        const int seg_hi = (seg_lo + SEGLEN < VV) ? (seg_lo + SEGLEN) : VV;
        const int n = seg_hi - seg_lo;
        const float* p0 = row + seg_lo;

        // peel to 16B alignment (row bases are only 4B-aligned)
        int head = (int)(((16u - (unsigned)((uintptr_t)p0 & 15u)) & 15u) >> 2);
        if (head > n) head = n;

        float a0 = 0.f, a1 = 0.f, a2 = 0.f, a3 = 0.f;
        for (int i = tid; i < head; i += 256) a0 += __expf(p0[i]);
        const float4* pv = (const float4*)(p0 + head);
        const int nvec = (n - head) >> 2;
        int i = tid;
        for (; i + 256 < nvec; i += 512) {   // 2 independent 16B loads in flight
            float4 x = pv[i];
            float4 y = pv[i + 256];
            a0 += __expf(x.x) + __expf(y.x);
            a1 += __expf(x.y) + __expf(y.y);
            a2 += __expf(x.z) + __expf(y.z);
            a3 += __expf(x.w) + __expf(y.w);
        }
        if (i < nvec) {
            float4 x = pv[i];
            a0 += __expf(x.x); a1 += __expf(x.y);
            a2 += __expf(x.z); a3 += __expf(x.w);
        }
        for (int k = head + (nvec << 2) + tid; k < n; k += 256) a0 += __expf(p0[k]);

        float acc = (a0 + a1) + (a2 + a3);
        #pragma unroll
        for (int off = 32; off >= 1; off >>= 1) acc += __shfl_xor(acc, off);
        if ((tid & 63) == 0) partial[((bt * NSEG + seg) << 2) + wv] = acc;

        // label numerators in this segment (cache-hot re-read, no barrier)
        if (tid < TT) {
            const int l = labels[b * TT + tid];
            if (l >= seg_lo && l < seg_hi) numer[bt * TT + tid] = __expf(row[l]);
        }
    }

    // ---- completion detection: last block runs the epilogue ----
    __threadfence();
    __syncthreads();
    if (tid == 0) {
        unsigned old = atomicAdd(counter, 1u);
        sh_last = (old == GRID1 - 1u) ? 1 : 0;
    }
    __syncthreads();
    if (!sh_last) return;
    __threadfence();   // acquire side

    // ---- epilogue: 8 b's per step, thread (g,tp) handles (b, label-slot tp) ----
    __shared__ float sinv_sh[8][TT];
    __shared__ float lsum[8];
    const int g  = tid >> 5;
    const int tp = tid & 31;
    float loss_local = 0.f;

    for (int bb = 0; bb < 8; ++bb) {
        const int b   = bb * 8 + g;
        const int len = cum[b + 1] - cum[b];
        float sv = 0.f;
        if (tp < len) {
            const float4* pp = (const float4*)&partial[(b * TT + tp) * (NSEG * 4)];
            float s = 0.f;
            #pragma unroll
            for (int q = 0; q < 8; ++q) { float4 v = pp[q]; s += (v.x + v.y) + (v.z + v.w); }
            sv = 1.0f / s;
        }
        sinv_sh[g][tp] = sv;
        __syncthreads();

        float agg = 0.f;
        for (int t = 0; t < len; ++t)
            agg += numer[(b * TT + t) * TT + tp] * sinv_sh[g][t];

        const int l = labels[b * TT + tp];
        float cov = 0.f, rep = 0.f, cnt = 0.f;
        if (l > 2) {
            cov = log1pf(__expf(-agg));     // -log(sigmoid(agg))
            const float d = 1.0f - agg;
            rep = d * d;
            cnt = 1.0f;
        }
        #pragma unroll
        for (int off = 16; off >= 1; off >>= 1) {
            cov += __shfl_xor(cov, off);
            rep += __shfl_xor(rep, off);
            cnt += __shfl_xor(cnt, off);
        }
        if (tp == 0) loss_local += (cov + rep) / cnt;
        __syncthreads();
    }
    if (tp == 0) lsum[g] = loss_local;
    __syncthreads();
    if (tid == 0) {
        float tot = 0.f;
        #pragma unroll
        for (int q = 0; q < 8; ++q) tot += lsum[q];
        out[0] = tot * (1.0f / BB);
    }
}

extern "C" void kernel_launch(void* const* d_in, const int* in_sizes, int n_in,
                              void* d_out, int out_size, void* d_ws, size_t ws_size,
                              hipStream_t stream) {
    const float* logits = (const float*)d_in[0];
    const int*   labels = (const int*)d_in[1];
    const int*   lens   = (const int*)d_in[2];
    float* out = (float*)d_out;

    unsigned* counter = (unsigned*)d_ws;
    float* partial = (float*)((char*)d_ws + 256);                         // 256 KB
    float* numer   = (float*)((char*)d_ws + 256 + BB*TT*NSEG*4*sizeof(float));

    hipMemsetD32Async((hipDeviceptr_t)counter, 0, 1, stream);
    fused_loss<<<GRID1, 256, 0, stream>>>(logits, labels, lens, counter, partial, numer, out);
}

// Round 6
// 69.214 us; speedup vs baseline: 4.4006x; 4.4006x over previous
//
#include <hip/hip_runtime.h>

#define BB 64
#define TT 32
#define VV 50257
#define GRID1 2048

// Kernel 1: byte-exact balanced streaming. Flat valid-element space
// E = nvalid*VV is split into 2048 equal ranges; each block covers <=2
// row-chunks. Per chunk: block sum of exp(x) (alignment-peeled float4),
// wave+LDS reduce, ONE plain store of (sum, bt). Label numerators gathered
// cache-hot. No atomics, no memsets, no device fences.
__global__ __launch_bounds__(256) void stream_sumexp(
    const float* __restrict__ logits,   // [B,T,V]
    const int*   __restrict__ labels,   // [B,T]
    const int*   __restrict__ lens,     // [B]
    float*       __restrict__ blk_sum,  // [GRID1*2]
    int*         __restrict__ blk_bt,   // [GRID1*2] (-1 = unused)
    float*       __restrict__ numer)    // [B*T][T]
{
    __shared__ int   cum[BB + 1];
    __shared__ float wsum[4];
    const int tid = threadIdx.x;

    if (tid < 64) {
        int inc = lens[tid];
        #pragma unroll
        for (int off = 1; off < 64; off <<= 1) {
            int o = __shfl_up(inc, off);
            if (tid >= off) inc += o;
        }
        cum[tid + 1] = inc;
        if (tid == 0) cum[0] = 0;
    }
    __syncthreads();
    const long long E = (long long)cum[BB] * VV;
    const int e_lo = (int)((E * blockIdx.x) / GRID1);
    const int e_hi = (int)((E * (blockIdx.x + 1)) / GRID1);
    const int r0 = e_lo / VV;
    const int r1 = (e_hi - 1) / VV;     // range <= VV -> at most 2 rows

    int c = 0;
    for (int r = r0; r <= r1; ++r, ++c) {
        int lo = 0, hi = BB;            // largest b with cum[b] <= r
        #pragma unroll
        for (int it = 0; it < 6; ++it) {
            const int mid = (lo + hi) >> 1;
            if (cum[mid] <= r) lo = mid; else hi = mid;
        }
        const int b  = lo;
        const int t  = r - cum[b];
        const int bt = b * TT + t;

        const int rbase = r * VV;                       // fits int (<104M)
        const int s_loc = (e_lo > rbase ? e_lo : rbase) - rbase;
        const int e_loc = ((e_hi < rbase + VV) ? e_hi : rbase + VV) - rbase;
        const int n = e_loc - s_loc;

        const float* row = logits + (size_t)bt * VV;
        const float* p0  = row + s_loc;

        // peel to 16B alignment (chunk bases are only 4B-aligned)
        int head = (int)(((16u - (unsigned)((uintptr_t)p0 & 15u)) & 15u) >> 2);
        if (head > n) head = n;

        float a0 = 0.f, a1 = 0.f, a2 = 0.f, a3 = 0.f;
        for (int i = tid; i < head; i += 256) a0 += __expf(p0[i]);
        const float4* pv = (const float4*)(p0 + head);
        const int nvec = (n - head) >> 2;
        for (int i = tid; i < nvec; i += 256) {
            float4 x = pv[i];
            a0 += __expf(x.x); a1 += __expf(x.y);
            a2 += __expf(x.z); a3 += __expf(x.w);
        }
        for (int k = head + (nvec << 2) + tid; k < n; k += 256) a0 += __expf(p0[k]);

        float acc = (a0 + a1) + (a2 + a3);
        #pragma unroll
        for (int off = 32; off >= 1; off >>= 1) acc += __shfl_xor(acc, off);
        if ((tid & 63) == 0) wsum[tid >> 6] = acc;
        __syncthreads();
        if (tid == 0) {
            blk_sum[blockIdx.x * 2 + c] = (wsum[0] + wsum[1]) + (wsum[2] + wsum[3]);
            blk_bt [blockIdx.x * 2 + c] = bt;
        }

        // label numerators in this chunk (cache-hot re-read)
        if (tid < TT) {
            const int l = labels[b * TT + tid];
            if (l >= s_loc && l < e_loc) numer[bt * TT + tid] = __expf(row[l]);
        }
        __syncthreads();   // protect wsum before possible second chunk
    }
    if (tid == 0 && c < 2) blk_bt[blockIdx.x * 2 + 1] = -1;
}

// Kernel 2: single block. LDS scatter-reduce of the 4096 (sum, bt) partials,
// then agg/loss epilogue, plain store to out. No atomics on global, no memset.
__global__ __launch_bounds__(256) void loss_reduce(
    const int*   __restrict__ labels,   // [B,T]
    const int*   __restrict__ lens,     // [B]
    const float* __restrict__ blk_sum,  // [GRID1*2]
    const int*   __restrict__ blk_bt,   // [GRID1*2]
    const float* __restrict__ numer,    // [B*T][T]
    float*       __restrict__ out)      // [1]
{
    __shared__ float s_inv[BB * TT];    // 8 KB
    __shared__ float lsum[8];
    const int tid = threadIdx.x;

    for (int i = tid; i < BB * TT; i += 256) s_inv[i] = 0.f;
    __syncthreads();
    for (int i = tid; i < GRID1 * 2; i += 256) {
        const int bt = blk_bt[i];
        if (bt >= 0) atomicAdd(&s_inv[bt], blk_sum[i]);
    }
    __syncthreads();
    for (int i = tid; i < BB * TT; i += 256) s_inv[i] = 1.0f / s_inv[i];
    __syncthreads();

    const int g  = tid >> 5;
    const int tp = tid & 31;
    float loss_local = 0.f;

    for (int rnd = 0; rnd < 8; ++rnd) {
        const int b   = rnd * 8 + g;
        const int len = lens[b];
        float agg = 0.f;
        for (int t = 0; t < len; ++t)
            agg += numer[(b * TT + t) * TT + tp] * s_inv[b * TT + t];

        const int l = labels[b * TT + tp];
        float cov = 0.f, rep = 0.f, cnt = 0.f;
        if (l > 2) {
            cov = log1pf(__expf(-agg));   // -log(sigmoid(agg))
            const float d = 1.0f - agg;
            rep = d * d;
            cnt = 1.0f;
        }
        #pragma unroll
        for (int off = 16; off >= 1; off >>= 1) {
            cov += __shfl_xor(cov, off);
            rep += __shfl_xor(rep, off);
            cnt += __shfl_xor(cnt, off);
        }
        if (tp == 0) loss_local += (cov + rep) / cnt;
    }
    if (tp == 0) lsum[g] = loss_local;
    __syncthreads();
    if (tid == 0) {
        float tot = 0.f;
        #pragma unroll
        for (int q = 0; q < 8; ++q) tot += lsum[q];
        out[0] = tot * (1.0f / BB);
    }
}

extern "C" void kernel_launch(void* const* d_in, const int* in_sizes, int n_in,
                              void* d_out, int out_size, void* d_ws, size_t ws_size,
                              hipStream_t stream) {
    const float* logits = (const float*)d_in[0];
    const int*   labels = (const int*)d_in[1];
    const int*   lens   = (const int*)d_in[2];
    float* out = (float*)d_out;

    float* blk_sum = (float*)d_ws;                                   // 16 KB
    int*   blk_bt  = (int*)((char*)d_ws + GRID1 * 2 * sizeof(float)); // 16 KB
    float* numer   = (float*)((char*)d_ws + 2 * GRID1 * 2 * sizeof(float));

    stream_sumexp<<<GRID1, 256, 0, stream>>>(logits, labels, lens, blk_sum, blk_bt, numer);
    loss_reduce<<<1, 256, 0, stream>>>(labels, lens, blk_sum, blk_bt, numer, out);
}

// Round 7
// 48.668 us; speedup vs baseline: 6.2585x; 1.4222x over previous
//
#include <hip/hip_runtime.h>

#define BB 64
#define TT 32
#define VV 50257
#define GRID1 2048

// Kernel 1: byte-exact balanced streaming (unchanged from R6). Flat valid-
// element space E = nvalid*VV split into 2048 equal ranges; each block covers
// <=2 row-chunks. Per chunk: block sum of exp(x), wave+LDS reduce, ONE plain
// store of (sum, bt). Label numerators gathered cache-hot. No atomics.
__global__ __launch_bounds__(256) void stream_sumexp(
    const float* __restrict__ logits,   // [B,T,V]
    const int*   __restrict__ labels,   // [B,T]
    const int*   __restrict__ lens,     // [B]
    float*       __restrict__ blk_sum,  // [GRID1*2]
    int*         __restrict__ blk_bt,   // [GRID1*2] (-1 = unused)
    float*       __restrict__ numer)    // [B*T][T]
{
    __shared__ int   cum[BB + 1];
    __shared__ float wsum[4];
    const int tid = threadIdx.x;

    if (tid < 64) {
        int inc = lens[tid];
        #pragma unroll
        for (int off = 1; off < 64; off <<= 1) {
            int o = __shfl_up(inc, off);
            if (tid >= off) inc += o;
        }
        cum[tid + 1] = inc;
        if (tid == 0) cum[0] = 0;
    }
    __syncthreads();
    const long long E = (long long)cum[BB] * VV;
    const int e_lo = (int)((E * blockIdx.x) / GRID1);
    const int e_hi = (int)((E * (blockIdx.x + 1)) / GRID1);
    const int r0 = e_lo / VV;
    const int r1 = (e_hi - 1) / VV;     // range <= VV -> at most 2 rows

    int c = 0;
    for (int r = r0; r <= r1; ++r, ++c) {
        int lo = 0, hi = BB;            // largest b with cum[b] <= r
        #pragma unroll
        for (int it = 0; it < 6; ++it) {
            const int mid = (lo + hi) >> 1;
            if (cum[mid] <= r) lo = mid; else hi = mid;
        }
        const int b  = lo;
        const int t  = r - cum[b];
        const int bt = b * TT + t;

        const int rbase = r * VV;
        const int s_loc = (e_lo > rbase ? e_lo : rbase) - rbase;
        const int e_loc = ((e_hi < rbase + VV) ? e_hi : rbase + VV) - rbase;
        const int n = e_loc - s_loc;

        const float* row = logits + (size_t)bt * VV;
        const float* p0  = row + s_loc;

        int head = (int)(((16u - (unsigned)((uintptr_t)p0 & 15u)) & 15u) >> 2);
        if (head > n) head = n;

        float a0 = 0.f, a1 = 0.f, a2 = 0.f, a3 = 0.f;
        for (int i = tid; i < head; i += 256) a0 += __expf(p0[i]);
        const float4* pv = (const float4*)(p0 + head);
        const int nvec = (n - head) >> 2;
        for (int i = tid; i < nvec; i += 256) {
            float4 x = pv[i];
            a0 += __expf(x.x); a1 += __expf(x.y);
            a2 += __expf(x.z); a3 += __expf(x.w);
        }
        for (int k = head + (nvec << 2) + tid; k < n; k += 256) a0 += __expf(p0[k]);

        float acc = (a0 + a1) + (a2 + a3);
        #pragma unroll
        for (int off = 32; off >= 1; off >>= 1) acc += __shfl_xor(acc, off);
        if ((tid & 63) == 0) wsum[tid >> 6] = acc;
        __syncthreads();
        if (tid == 0) {
            blk_sum[blockIdx.x * 2 + c] = (wsum[0] + wsum[1]) + (wsum[2] + wsum[3]);
            blk_bt [blockIdx.x * 2 + c] = bt;
        }

        if (tid < TT) {
            const int l = labels[b * TT + tid];
            if (l >= s_loc && l < e_loc) numer[bt * TT + tid] = __expf(row[l]);
        }
        __syncthreads();
    }
    if (tid == 0 && c < 2) blk_bt[blockIdx.x * 2 + 1] = -1;
}

// Kernel 2: 64 blocks, one per sample b. Phase 1: scan the 4096 partials
// (L2/L3-hot) into LDS s_sum[32]. Phase 2: parallel (t-group x tp) product
// accumulation + LDS tree. Phase 3: loss terms on 32 lanes, one atomicAdd
// per block into out.
__global__ __launch_bounds__(256) void loss_reduce(
    const int*   __restrict__ labels,   // [B,T]
    const int*   __restrict__ lens,     // [B]
    const float* __restrict__ blk_sum,  // [GRID1*2]
    const int*   __restrict__ blk_bt,   // [GRID1*2]
    const float* __restrict__ numer,    // [B*T][T]
    float*       __restrict__ out)      // [1] (zeroed)
{
    const int b   = blockIdx.x;
    const int tid = threadIdx.x;
    const int len = lens[b];
    const int base = b * TT;

    __shared__ float s_sum[TT];
    __shared__ float s_inv[TT];
    __shared__ float aggp[8][TT];

    if (tid < TT) s_sum[tid] = 0.f;
    __syncthreads();

    for (int i = tid; i < GRID1 * 2; i += 256) {
        const int bt = blk_bt[i];
        if (bt >= base && bt < base + TT) atomicAdd(&s_sum[bt - base], blk_sum[i]);
    }
    __syncthreads();
    if (tid < TT) s_inv[tid] = 1.0f / s_sum[tid];   // t>=len: inf, never read
    __syncthreads();

    const int tg = tid >> 5;
    const int tp = tid & 31;
    float a = 0.f;
    for (int t = tg; t < len; t += 8)
        a += numer[(base + t) * TT + tp] * s_inv[t];
    aggp[tg][tp] = a;
    __syncthreads();

    if (tid < TT) {
        float agg = 0.f;
        #pragma unroll
        for (int q = 0; q < 8; ++q) agg += aggp[q][tid];

        const int l = labels[base + tid];
        float cov = 0.f, rep = 0.f, cnt = 0.f;
        if (l > 2) {
            cov = log1pf(__expf(-agg));   // -log(sigmoid(agg))
            const float d = 1.0f - agg;
            rep = d * d;
            cnt = 1.0f;
        }
        #pragma unroll
        for (int off = 16; off >= 1; off >>= 1) {
            cov += __shfl_xor(cov, off);
            rep += __shfl_xor(rep, off);
            cnt += __shfl_xor(cnt, off);
        }
        if (tid == 0) atomicAdd(out, (cov + rep) / cnt * (1.0f / BB));
    }
}

extern "C" void kernel_launch(void* const* d_in, const int* in_sizes, int n_in,
                              void* d_out, int out_size, void* d_ws, size_t ws_size,
                              hipStream_t stream) {
    const float* logits = (const float*)d_in[0];
    const int*   labels = (const int*)d_in[1];
    const int*   lens   = (const int*)d_in[2];
    float* out = (float*)d_out;

    float* blk_sum = (float*)d_ws;                                    // 16 KB
    int*   blk_bt  = (int*)((char*)d_ws + GRID1 * 2 * sizeof(float)); // 16 KB
    float* numer   = (float*)((char*)d_ws + 2 * GRID1 * 2 * sizeof(float));

    hipMemsetAsync(out, 0, sizeof(float), stream);
    stream_sumexp<<<GRID1, 256, 0, stream>>>(logits, labels, lens, blk_sum, blk_bt, numer);
    loss_reduce<<<BB, 256, 0, stream>>>(labels, lens, blk_sum, blk_bt, numer, out);
}

// Round 8
// 44.061 us; speedup vs baseline: 6.9127x; 1.1045x over previous
//
#include <hip/hip_runtime.h>

#define BB 64
#define TT 32
#define VV 50257
#define GRID1 2048

// Kernel 1: pure streaming sum-exp, byte-exact balanced, ZERO barriers in the
// hot path. Flat valid-element space E = nvalid*VV split into 2048 equal
// ranges (<=2 row-chunks each). Each wave stores its own partial (plain store,
// distinct address) -> no LDS reduce, no per-chunk __syncthreads. Block 0 also
// zeroes out[0] (visible to k2 across the kernel boundary).
__global__ __launch_bounds__(256) void stream_sumexp(
    const float* __restrict__ logits,   // [B,T,V]
    const int*   __restrict__ lens,     // [B]
    int*         __restrict__ blk_bt,   // [GRID1*2] (-1 = unused)
    float*       __restrict__ blk_sum,  // [GRID1*2][4] per-wave partials
    float*       __restrict__ out)      // [1] zeroed here
{
    __shared__ int cum[BB + 1];
    const int tid = threadIdx.x;
    const int wv  = tid >> 6;

    if (blockIdx.x == 0 && tid == 0) out[0] = 0.f;

    if (tid < 64) {
        int inc = lens[tid];
        #pragma unroll
        for (int off = 1; off < 64; off <<= 1) {
            int o = __shfl_up(inc, off);
            if (tid >= off) inc += o;
        }
        cum[tid + 1] = inc;
        if (tid == 0) cum[0] = 0;
    }
    __syncthreads();
    const long long E = (long long)cum[BB] * VV;
    const int e_lo = (int)((E * blockIdx.x) / GRID1);
    const int e_hi = (int)((E * (blockIdx.x + 1)) / GRID1);
    const int r0 = e_lo / VV;
    const int r1 = (e_hi - 1) / VV;     // chunk <= VV -> at most 2 rows

    int c = 0;
    for (int r = r0; r <= r1; ++r, ++c) {
        int lo = 0, hi = BB;            // largest b with cum[b] <= r
        #pragma unroll
        for (int it = 0; it < 6; ++it) {
            const int mid = (lo + hi) >> 1;
            if (cum[mid] <= r) lo = mid; else hi = mid;
        }
        const int b  = lo;
        const int t  = r - cum[b];
        const int bt = b * TT + t;

        const int rbase = r * VV;
        const int s_loc = (e_lo > rbase ? e_lo : rbase) - rbase;
        const int e_loc = ((e_hi < rbase + VV) ? e_hi : rbase + VV) - rbase;
        const int n = e_loc - s_loc;

        const float* p0 = logits + (size_t)bt * VV + s_loc;

        // peel to 16B alignment (chunk bases are only 4B-aligned)
        int head = (int)(((16u - (unsigned)((uintptr_t)p0 & 15u)) & 15u) >> 2);
        if (head > n) head = n;

        float a0 = 0.f, a1 = 0.f, a2 = 0.f, a3 = 0.f;
        for (int i = tid; i < head; i += 256) a0 += __expf(p0[i]);
        const float4* pv = (const float4*)(p0 + head);
        const int nvec = (n - head) >> 2;
        int i = tid;
        for (; i + 256 < nvec; i += 512) {   // 2 independent 16B loads in flight
            float4 x = pv[i];
            float4 y = pv[i + 256];
            a0 += __expf(x.x) + __expf(y.x);
            a1 += __expf(x.y) + __expf(y.y);
            a2 += __expf(x.z) + __expf(y.z);
            a3 += __expf(x.w) + __expf(y.w);
        }
        if (i < nvec) {
            float4 x = pv[i];
            a0 += __expf(x.x); a1 += __expf(x.y);
            a2 += __expf(x.z); a3 += __expf(x.w);
        }
        for (int k = head + (nvec << 2) + tid; k < n; k += 256) a0 += __expf(p0[k]);

        float acc = (a0 + a1) + (a2 + a3);
        #pragma unroll
        for (int off = 32; off >= 1; off >>= 1) acc += __shfl_xor(acc, off);
        if ((tid & 63) == 0) blk_sum[((blockIdx.x * 2 + c) << 2) + wv] = acc;
        if (tid == 0)        blk_bt [blockIdx.x * 2 + c] = bt;
    }
    if (tid == 0 && c < 2) blk_bt[blockIdx.x * 2 + 1] = -1;
}

// Kernel 2: 64 blocks, one per sample. Phase 1: scan 4096 (bt, sum[4])
// partials into LDS s_sum. Phase 2: invert. Phase 3: gather exp(logits[t][l])
// directly (loop-independent addresses -> concurrent loads) and accumulate
// agg. Phase 4: loss terms, one atomicAdd per block into out.
__global__ __launch_bounds__(256) void loss_reduce(
    const float* __restrict__ logits,   // [B,T,V]
    const int*   __restrict__ labels,   // [B,T]
    const int*   __restrict__ lens,     // [B]
    const int*   __restrict__ blk_bt,   // [GRID1*2]
    const float* __restrict__ blk_sum,  // [GRID1*2][4]
    float*       __restrict__ out)      // [1] (zeroed by k1)
{
    const int b    = blockIdx.x;
    const int tid  = threadIdx.x;
    const int len  = lens[b];
    const int base = b * TT;

    __shared__ float s_sum[TT];
    __shared__ float s_inv[TT];
    __shared__ int   s_lab[TT];
    __shared__ float aggp[8][TT];

    if (tid < TT) { s_sum[tid] = 0.f; s_lab[tid] = labels[base + tid]; }
    __syncthreads();

    const float4* bs4 = (const float4*)blk_sum;
    for (int i = tid; i < GRID1 * 2; i += 256) {
        const int bt = blk_bt[i];
        if (bt >= base && bt < base + TT) {
            float4 v = bs4[i];
            atomicAdd(&s_sum[bt - base], (v.x + v.y) + (v.z + v.w));
        }
    }
    __syncthreads();
    if (tid < TT) s_inv[tid] = 1.0f / s_sum[tid];   // t>=len: never read
    __syncthreads();

    const int tg = tid >> 5;
    const int tp = tid & 31;
    const int l  = s_lab[tp];
    float a = 0.f;
    for (int t = tg; t < len; t += 8)
        a += __expf(logits[(size_t)(base + t) * VV + l]) * s_inv[t];
    aggp[tg][tp] = a;
    __syncthreads();

    if (tid < TT) {
        float agg = 0.f;
        #pragma unroll
        for (int q = 0; q < 8; ++q) agg += aggp[q][tid];

        float cov = 0.f, rep = 0.f, cnt = 0.f;
        if (s_lab[tid] > 2) {
            cov = log1pf(__expf(-agg));   // -log(sigmoid(agg))
            const float d = 1.0f - agg;
            rep = d * d;
            cnt = 1.0f;
        }
        #pragma unroll
        for (int off = 16; off >= 1; off >>= 1) {
            cov += __shfl_xor(cov, off);
            rep += __shfl_xor(rep, off);
            cnt += __shfl_xor(cnt, off);
        }
        if (tid == 0) atomicAdd(out, (cov + rep) / cnt * (1.0f / BB));
    }
}

extern "C" void kernel_launch(void* const* d_in, const int* in_sizes, int n_in,
                              void* d_out, int out_size, void* d_ws, size_t ws_size,
                              hipStream_t stream) {
    const float* logits = (const float*)d_in[0];
    const int*   labels = (const int*)d_in[1];
    const int*   lens   = (const int*)d_in[2];
    float* out = (float*)d_out;

    int*   blk_bt  = (int*)d_ws;                        // 16 KB
    float* blk_sum = (float*)((char*)d_ws + GRID1 * 2 * sizeof(int));  // 64 KB, 16B-aligned

    stream_sumexp<<<GRID1, 256, 0, stream>>>(logits, lens, blk_bt, blk_sum, out);
    loss_reduce<<<BB, 256, 0, stream>>>(logits, labels, lens, blk_bt, blk_sum, out);
}